// Round 1
// baseline (34.249 us; speedup 1.0000x reference)
//
#include <hip/hip_runtime.h>
#include <math.h>

#define T_SAMPLES 100
#define MM_BLOCKS 256
#define HIST_BLOCKS 256
#define THREADS 256

// ws layout (float* f = (float*)d_ws, unsigned* u = (unsigned*)d_ws):
//   f[0], f[1]                         : t_min, t_max (of losses)
//   f[16 .. 16+MM_BLOCKS)              : per-block min partials
//   f[16+MM_BLOCKS .. 16+2*MM_BLOCKS)  : per-block max partials
//   u[1024 .. 1024+T_SAMPLES)          : global hist counts
//   f[1152 .. 1152+T_SAMPLES)          : global hist sums
// Total ws use < 8 KB.

__global__ void cvar_minmax_kernel(const float* __restrict__ pnl, int n,
                                   float* __restrict__ ws) {
    int tid = blockIdx.x * blockDim.x + threadIdx.x;
    int stride = gridDim.x * blockDim.x;
    float lmin = INFINITY, lmax = -INFINITY;
    int n4 = n >> 2;
    const float4* p4 = (const float4*)pnl;
    for (int i = tid; i < n4; i += stride) {
        float4 v = p4[i];
        float a = -v.x, b = -v.y, c = -v.z, d = -v.w;  // losses = -pnl
        lmin = fminf(lmin, fminf(fminf(a, b), fminf(c, d)));
        lmax = fmaxf(lmax, fmaxf(fmaxf(a, b), fmaxf(c, d)));
    }
    for (int i = (n4 << 2) + tid; i < n; i += stride) {
        float l = -pnl[i];
        lmin = fminf(lmin, l);
        lmax = fmaxf(lmax, l);
    }
    #pragma unroll
    for (int off = 32; off > 0; off >>= 1) {
        lmin = fminf(lmin, __shfl_down(lmin, off, 64));
        lmax = fmaxf(lmax, __shfl_down(lmax, off, 64));
    }
    __shared__ float smin[THREADS / 64];
    __shared__ float smax[THREADS / 64];
    int lane = threadIdx.x & 63, wid = threadIdx.x >> 6;
    if (lane == 0) { smin[wid] = lmin; smax[wid] = lmax; }
    __syncthreads();
    if (threadIdx.x == 0) {
        float bmin = smin[0], bmax = smax[0];
        for (int w = 1; w < THREADS / 64; ++w) {
            bmin = fminf(bmin, smin[w]);
            bmax = fmaxf(bmax, smax[w]);
        }
        ws[16 + blockIdx.x] = bmin;
        ws[16 + MM_BLOCKS + blockIdx.x] = bmax;
    }
}

// One block of MM_BLOCKS threads: final min/max reduce + zero global hist.
__global__ void cvar_mm_final_kernel(float* __restrict__ ws) {
    float lmin = ws[16 + threadIdx.x];
    float lmax = ws[16 + MM_BLOCKS + threadIdx.x];
    #pragma unroll
    for (int off = 32; off > 0; off >>= 1) {
        lmin = fminf(lmin, __shfl_down(lmin, off, 64));
        lmax = fmaxf(lmax, __shfl_down(lmax, off, 64));
    }
    __shared__ float smin[MM_BLOCKS / 64];
    __shared__ float smax[MM_BLOCKS / 64];
    int lane = threadIdx.x & 63, wid = threadIdx.x >> 6;
    if (lane == 0) { smin[wid] = lmin; smax[wid] = lmax; }
    __syncthreads();
    if (threadIdx.x == 0) {
        float bmin = smin[0], bmax = smax[0];
        for (int w = 1; w < MM_BLOCKS / 64; ++w) {
            bmin = fminf(bmin, smin[w]);
            bmax = fmaxf(bmax, smax[w]);
        }
        ws[0] = bmin;
        ws[1] = bmax;
    }
    // zero the global histogram for this call (ws is NOT re-poisoned between replays)
    unsigned* gcnt = (unsigned*)ws + 1024;
    float* gsum = ws + 1152;
    if (threadIdx.x < T_SAMPLES) {
        gcnt[threadIdx.x] = 0u;
        gsum[threadIdx.x] = 0.0f;
    }
}

__global__ void cvar_hist_kernel(const float* __restrict__ pnl, int n,
                                 float* __restrict__ ws) {
    __shared__ unsigned scnt[T_SAMPLES];
    __shared__ float ssum[T_SAMPLES];
    if (threadIdx.x < T_SAMPLES) { scnt[threadIdx.x] = 0u; ssum[threadIdx.x] = 0.0f; }
    __syncthreads();

    float t_min = ws[0], t_max = ws[1];
    float range = t_max - t_min;
    float inv_dt = (range > 0.0f) ? (float)(T_SAMPLES - 1) / range : 0.0f;

    int tid = blockIdx.x * blockDim.x + threadIdx.x;
    int stride = gridDim.x * blockDim.x;
    int n4 = n >> 2;
    const float4* p4 = (const float4*)pnl;
    for (int i = tid; i < n4; i += stride) {
        float4 v = p4[i];
        float l[4] = {-v.x, -v.y, -v.z, -v.w};
        #pragma unroll
        for (int k = 0; k < 4; ++k) {
            int b = (int)((l[k] - t_min) * inv_dt);   // >= 0 since t_min is global min
            b = b < 0 ? 0 : (b > T_SAMPLES - 1 ? T_SAMPLES - 1 : b);
            atomicAdd(&scnt[b], 1u);
            atomicAdd(&ssum[b], l[k]);
        }
    }
    for (int i = (n4 << 2) + tid; i < n; i += stride) {
        float l = -pnl[i];
        int b = (int)((l - t_min) * inv_dt);
        b = b < 0 ? 0 : (b > T_SAMPLES - 1 ? T_SAMPLES - 1 : b);
        atomicAdd(&scnt[b], 1u);
        atomicAdd(&ssum[b], l);
    }
    __syncthreads();

    unsigned* gcnt = (unsigned*)ws + 1024;
    float* gsum = ws + 1152;
    if (threadIdx.x < T_SAMPLES) {
        unsigned c = scnt[threadIdx.x];
        if (c) {
            atomicAdd(&gcnt[threadIdx.x], c);
            atomicAdd(&gsum[threadIdx.x], ssum[threadIdx.x]);
        }
    }
}

// One block of 128 threads: suffix sums over 100 bins -> cvar_j -> min.
__global__ void cvar_final_kernel(const float* __restrict__ ws,
                                  float* __restrict__ out, int n) {
    __shared__ unsigned s_cnt[T_SAMPLES];
    __shared__ float s_sum[T_SAMPLES];
    int j = threadIdx.x;
    const unsigned* gcnt = (const unsigned*)ws + 1024;
    const float* gsum = ws + 1152;
    if (j < T_SAMPLES) { s_cnt[j] = gcnt[j]; s_sum[j] = gsum[j]; }
    __syncthreads();

    float t_min = ws[0], t_max = ws[1];
    float dt = (t_max - t_min) / (float)(T_SAMPLES - 1);

    float cvar = INFINITY;
    if (j < T_SAMPLES) {
        float L = 0.0f;
        unsigned C = 0;
        for (int k = j; k < T_SAMPLES; ++k) { L += s_sum[k]; C += s_cnt[k]; }
        float tj = (j == T_SAMPLES - 1) ? t_max : t_min + (float)j * dt;
        float S = L - tj * (float)C;               // == sum relu(l - tj)
        cvar = tj + (S / (float)n) * 20.0f;        // mean / (1 - 0.95)
    }
    #pragma unroll
    for (int off = 32; off > 0; off >>= 1)
        cvar = fminf(cvar, __shfl_down(cvar, off, 64));
    __shared__ float sred[2];
    int lane = threadIdx.x & 63, wid = threadIdx.x >> 6;
    if (lane == 0) sred[wid] = cvar;
    __syncthreads();
    if (threadIdx.x == 0) out[0] = fminf(sred[0], sred[1]);
}

extern "C" void kernel_launch(void* const* d_in, const int* in_sizes, int n_in,
                              void* d_out, int out_size, void* d_ws, size_t ws_size,
                              hipStream_t stream) {
    const float* pnl = (const float*)d_in[0];
    int n = in_sizes[0];
    float* ws = (float*)d_ws;
    float* out = (float*)d_out;

    cvar_minmax_kernel<<<MM_BLOCKS, THREADS, 0, stream>>>(pnl, n, ws);
    cvar_mm_final_kernel<<<1, MM_BLOCKS, 0, stream>>>(ws);
    cvar_hist_kernel<<<HIST_BLOCKS, THREADS, 0, stream>>>(pnl, n, ws);
    cvar_final_kernel<<<1, 128, 0, stream>>>(ws, out, n);
}